// Round 3
// baseline (297.817 us; speedup 1.0000x reference)
//
#include <hip/hip_runtime.h>

// Temporal shift: B=64, T=128, N=21, C=256, U=1.
// Partitions of C: [0,86) shift -1 (out[t]=x[t+1]); [86,171) shift 0;
// [171,256) shift +1 (out[t]=x[t-1]). Zero-fill out-of-range t.
// Layout (B,T,N,C) row-major: t-stride = N*C = 5376 floats = 1344 float4.
//
// v4 design — branch-free blend + 2 elements/thread + predicated B-load:
//  - v3 (~71us kernel slice) was limited by (1) every lane issuing a second
//    redundant load (62/64 lanes have B-addr == A-addr -> 2x L1 request
//    count) and (2) one load->store chain per thread (shallow MLP).
//  - Each thread handles float4 i and i + TOTAL/2. TOTAL/2 = 5,505,024 =
//    4096 (b,t)-slices exactly, so both elements share the same t, c4,
//    shift classification and validity -> classify once, issue A0/A1
//    back-to-back (2x outstanding loads), store two contiguous 1024B wave
//    stores.
//  - B loads are exec-predicated: only the 2 straddle lanes (c4==21, 42)
//    issue them; the branch feeds registers only (no divergent stores).
//  - 256-thread blocks, cached (non-NT) loads+stores.

typedef float v4f __attribute__((ext_vector_type(4)));

#define NT_T 128
#define NT_N 21
#define NT_C 256
#define T_STRIDE_V (NT_N * NT_C / 4)       // 1344 float4 per t step
#define TOTAL_V    11010048                // 64*128*21*256/4
#define HALF_V     (TOTAL_V / 2)           // 5,505,024 = 21504 * 256

__global__ __launch_bounds__(256) void temporal_shift_kernel(
    const v4f* __restrict__ xv, v4f* __restrict__ ov)
{
    const int i = blockIdx.x * 256 + threadIdx.x;   // < HALF_V (exact grid)

    const int c4  = i & 63;                 // float4-group within C (64/row)
    const int row = i >> 6;                 // (b,t,n) row index
    const int t   = (row / NT_N) & (NT_T - 1);

    // Component shifts: s(c) = c<86 ? -1 : c<171 ? 0 : +1.
    // Within a group, comps 0..1 share s0; comp 2 differs only at c4==21;
    // comp 3 differs at c4==21 and c4==42.
    const int c0 = c4 << 2;
    const int s0 = (c0 < 86) ? -1 : ((c0 < 171) ? 0 : 1);
    const int s3 = (c0 + 3 < 86) ? -1 : ((c0 + 3 < 171) ? 0 : 1);

    const bool vA = ((unsigned)(t - s0)) < (unsigned)NT_T;
    const bool vB = ((unsigned)(t - s3)) < (unsigned)NT_T;
    const int offA = vA ? -s0 * T_STRIDE_V : 0;   // clamped in-bounds
    const int offB = vB ? -s3 * T_STRIDE_V : 0;

    const v4f zero = {0.f, 0.f, 0.f, 0.f};

    // Primary loads for both elements, issued back-to-back.
    v4f A0 = xv[i + offA];
    v4f A1 = xv[i + HALF_V + offA];

    // Secondary loads only on the two straddle lanes per wave.
    v4f B0 = zero, B1 = zero;
    const bool needB = (s3 != s0);          // c4==21 || c4==42
    if (needB) {
        B0 = xv[i + offB];
        B1 = xv[i + HALF_V + offB];
        if (!vB) { B0 = zero; B1 = zero; }
    }
    if (!vA) { A0 = zero; A1 = zero; }

    v4f r0, r1;
    r0.x = A0.x;  r0.y = A0.y;
    r1.x = A1.x;  r1.y = A1.y;
    r0.z = (c4 == 21) ? B0.z : A0.z;
    r1.z = (c4 == 21) ? B1.z : A1.z;
    r0.w = needB ? B0.w : A0.w;
    r1.w = needB ? B1.w : A1.w;

    ov[i]          = r0;
    ov[i + HALF_V] = r1;
}

extern "C" void kernel_launch(void* const* d_in, const int* in_sizes, int n_in,
                              void* d_out, int out_size, void* d_ws, size_t ws_size,
                              hipStream_t stream)
{
    const v4f* x = (const v4f*)d_in[0];
    v4f* out = (v4f*)d_out;
    const int grid = HALF_V / 256;   // 21504 blocks, exact
    temporal_shift_kernel<<<grid, 256, 0, stream>>>(x, out);
}